// Round 4
// baseline (251.250 us; speedup 1.0000x reference)
//
#include <hip/hip_runtime.h>

// MLoss: masked box-MSE + face-BCE + background-BCE over [B=2048, N=2704, C=5].
// 221.5 MB read once per launch. Reduce kernel history:
//   R2   atomic-free two-stage reduction          (atomics = 270 us wall)
//   R3-5 82-84 us invariant to occupancy/VGPR/LDS/MLP probes
//   R6   shfl for neighbor conf + nontemporal x -> 66 us
//   R7/8 reg double-buffer @ launch_bounds(256,8) -> spilled to scratch, 72 us
//   R9   same pipeline @ (256,4): spill gone (WRITE 64B), VGPR 40, pipeline
//        live -- and STILL 65 us. Little's law: 3.4 TB/s at ~2KB/wave in
//        flight => effective latency ~5400 cy. Register-side MLP is falsified
//        as the lever; either a pattern-specific service wall (nt bypass
//        path?) or in-flight is lower than source order implies.
// R10: structural rewrite. Per-WAVE contiguous walk of 1KB slices with a
//      depth-4 global_load_lds DMA ring (regalloc-free MLP: 8KB/wave in
//      flight, 20 waves/CU = 160KB/CU), counted s_waitcnt vmcnt(6) (never 0
//      in-loop), no barriers (each wave consumes only its own slices; conf
//      neighbor via __shfl + one-register carry across steps, global
//      broadcast load only for the wave's very first cell). aux=0 drops
//      nontemporal: x allocates normally; x+y=221.5MB ~fits 256MB L3.
//      FETCH_SIZE is the nt-diagnostic: ~30-60MB => L3-resident, ~221MB not.

#define BLOCK 256
#define WPB   (BLOCK / 64)       // waves per block
#define DEPTH 4                  // DMA pipeline depth (slices in flight)
#define LOG_CLAMP -100.0f

typedef float nvec4 __attribute__((ext_vector_type(4)));

__device__ __forceinline__ float clogf(float v) {
    return fmaxf(logf(v), LOG_CLAMP);
}

// Stage one 1KB x-slice + 1KB y-slice into this wave's LDS ring buffer.
// Global source is per-lane (sg+lane), LDS dest is wave-uniform; HW lands
// lane l's 16B at ldsx + l*16 (m104 semantics). vmcnt += 2 per call.
__device__ __forceinline__ void stage_slice(
    const nvec4* __restrict__ gx4, const nvec4* __restrict__ gy4,
    int sg, float* ldsx, int lane)
{
    __builtin_amdgcn_global_load_lds(
        (const __attribute__((address_space(1))) void*)(gx4 + sg + lane),
        (__attribute__((address_space(3))) void*)ldsx, 16, 0, 0);
    __builtin_amdgcn_global_load_lds(
        (const __attribute__((address_space(1))) void*)(gy4 + sg + lane),
        (__attribute__((address_space(3))) void*)(ldsx + 256), 16, 0, 0);
}

// Stage 1: each wave owns a contiguous span of `steps` slices (64 groups =
// 1KB per array per slice, one group of 4 floats per lane per step).
__global__ __launch_bounds__(BLOCK) void mloss_reduce(
    const float* __restrict__ x, const float* __restrict__ y,
    float4* __restrict__ partials, int nsteps_total, int nw)
{
    const int lane = threadIdx.x & 63;
    const int wv   = threadIdx.x >> 6;
    const int wid  = blockIdx.x * WPB + wv;

    __shared__ float lds[WPB][DEPTH][512];   // [wave][ring][x:0..255 | y:256..511]

    const nvec4* gx4 = (const nvec4*)x;
    const nvec4* gy4 = (const nvec4*)y;

    float s_sq = 0.0f, s_bce = 0.0f, s_bg = 0.0f, s_cnt = 0.0f;

    const int S = nsteps_total / nw;
    const int R = nsteps_total % nw;
    const int steps = (wid < nw) ? (S + (wid < R ? 1 : 0)) : 0;
    const int start = wid * S + (wid < R ? wid : R);
    const int wgb   = start * 64;            // this wave's first group index

    if (steps > 0) {
        // Carry-in: conf of the cell containing the wave's first element.
        // Wave-uniform address -> broadcast load, one line.
        const int e00 = wgb * 4;
        float carry = y[e00 - (e00 % 5)];

        // r = e0 % 5 for this lane; advances +1 mod 5 per step (delta 256).
        int r = (e00 + lane * 4) % 5;

        // Consume slice t from the ring; updates r and carry.
        auto consume = [&](int t) {
            const float* Lx = &lds[wv][t & (DEPTH - 1)][0];
            const nvec4 X = *(const nvec4*)(Lx + lane * 4);
            const nvec4 Y = *(const nvec4*)(Lx + 256 + lane * 4);

            // Conf element of the cell starting inside this group (r != 1).
            const int jc = (5 - r) % 5;
            const float tnext = (jc == 0) ? Y.x : (jc == 1) ? Y.y : (jc == 2) ? Y.z : Y.w;
            const float pconf = (jc == 0) ? X.x : (jc == 1) ? X.y : (jc == 2) ? X.z : X.w;
            const bool  has_conf = (r != 1);

            const float lp  = clogf(pconf);
            const float l1p = clogf(1.0f - pconf);
            const bool  mc  = tnext > 0.5f;
            s_bce += (has_conf && mc)  ? -(tnext * lp + (1.0f - tnext) * l1p) : 0.0f;
            s_bg  += (has_conf && !mc) ? -l1p : 0.0f;
            s_cnt += (has_conf && mc)  ? 1.0f : 0.0f;

            // Conf of the cell containing e0, from the neighbor group:
            // sender r=0 -> Y.x, r=2 -> Y.w, r=3 -> Y.z, r=4 -> Y.y.
            const float outv = (r == 0) ? Y.x : (r == 2) ? Y.w : (r == 3) ? Y.z : Y.y;
            float ycp = __shfl_up(outv, 1, 64);
            if (lane == 0) ycp = carry;           // lane63's outv, previous step
            carry = __shfl(outv, 63, 64);
            const float yc = (r == 0) ? Y.x : ycp;

            #define MLOSS_BOX(J, XJ, YJ) do {                                 \
                const int   m  = r + (J);                                     \
                const bool  ic = (m == 0) || (m == 5);                        \
                const float tj = (m >= 5) ? tnext : yc;                       \
                const float d  = (XJ) - (YJ);                                 \
                s_sq += (!ic && tj > 0.5f) ? d * d : 0.0f;                    \
            } while (0)
            MLOSS_BOX(0, X.x, Y.x);
            MLOSS_BOX(1, X.y, Y.y);
            MLOSS_BOX(2, X.z, Y.z);
            MLOSS_BOX(3, X.w, Y.w);
            #undef MLOSS_BOX

            r = (r == 4) ? 0 : r + 1;
        };

        // Prologue: fill the ring.
        #pragma unroll
        for (int j = 0; j < DEPTH; ++j)
            if (j < steps)
                stage_slice(gx4, gy4, wgb + j * 64, &lds[wv][j][0], lane);

        // Main: wait only for slice t (vmcnt(6) = 3 slices still flying),
        // consume it, refill its ring slot with slice t+DEPTH.
        int t = 0;
        for (; t + DEPTH < steps; ++t) {
            asm volatile("s_waitcnt vmcnt(6)" ::: "memory");
            __builtin_amdgcn_sched_barrier(0);
            consume(t);
            __builtin_amdgcn_sched_barrier(0);   // keep ds_reads before the overwrite DMA
            stage_slice(gx4, gy4, wgb + (t + DEPTH) * 64,
                        &lds[wv][t & (DEPTH - 1)][0], lane);
        }
        // Epilogue: drain once, consume the last <=DEPTH slices.
        asm volatile("s_waitcnt vmcnt(0)" ::: "memory");
        __builtin_amdgcn_sched_barrier(0);
        for (; t < steps; ++t) consume(t);
    }

    // ---- Wave-64 butterfly reduce, then cross-wave via LDS ----
    #pragma unroll
    for (int off = 32; off > 0; off >>= 1) {
        s_sq  += __shfl_down(s_sq,  off, 64);
        s_bce += __shfl_down(s_bce, off, 64);
        s_bg  += __shfl_down(s_bg,  off, 64);
        s_cnt += __shfl_down(s_cnt, off, 64);
    }
    __shared__ float4 r_part[WPB];
    if (lane == 0) r_part[wv] = make_float4(s_sq, s_bce, s_bg, s_cnt);
    __syncthreads();
    if (threadIdx.x == 0) {
        float4 t0 = r_part[0];
        #pragma unroll
        for (int w = 1; w < WPB; ++w) {
            t0.x += r_part[w].x; t0.y += r_part[w].y;
            t0.z += r_part[w].z; t0.w += r_part[w].w;
        }
        partials[blockIdx.x] = t0;
    }
}

// Stage 2: one block reduces per-block partials (double accumulation),
// mops up tail elements not covered by full slices, computes the scalar.
#define FBLOCK 1024
__global__ __launch_bounds__(FBLOCK) void mloss_final(
    const float4* __restrict__ partials, int n_parts,
    const float* __restrict__ x, const float* __restrict__ y,
    float* __restrict__ out, long long elem_start, long long n_elems,
    long long n_cells)
{
    double s_sq = 0.0, s_bce = 0.0, s_bg = 0.0, s_cnt = 0.0;
    for (int i = threadIdx.x; i < n_parts; i += FBLOCK) {
        const float4 v = partials[i];
        s_sq += (double)v.x; s_bce += (double)v.y;
        s_bg += (double)v.z; s_cnt += (double)v.w;
    }

    #pragma unroll
    for (int off = 32; off > 0; off >>= 1) {
        s_sq  += __shfl_down(s_sq,  off, 64);
        s_bce += __shfl_down(s_bce, off, 64);
        s_bg  += __shfl_down(s_bg,  off, 64);
        s_cnt += __shfl_down(s_cnt, off, 64);
    }

    __shared__ double r[FBLOCK / 64][4];
    const int wave = threadIdx.x >> 6;
    const int lane = threadIdx.x & 63;
    if (lane == 0) { r[wave][0] = s_sq; r[wave][1] = s_bce; r[wave][2] = s_bg; r[wave][3] = s_cnt; }
    __syncthreads();

    if (threadIdx.x == 0) {
        double t_sq = 0.0, t_bce = 0.0, t_bg = 0.0, face = 0.0;
        #pragma unroll
        for (int w = 0; w < FBLOCK / 64; ++w) {
            t_sq += r[w][0]; t_bce += r[w][1]; t_bg += r[w][2]; face += r[w][3];
        }
        for (long long e = elem_start; e < n_elems; ++e) {
            const long long m  = e % 5;
            const float t_cell = y[e - m];
            const bool  mask   = t_cell > 0.5f;
            if (m == 0) {
                const float p   = x[e];
                const float lp  = clogf(p);
                const float l1p = clogf(1.0f - p);
                if (mask) { t_bce += (double)(-(t_cell * lp + (1.0f - t_cell) * l1p)); face += 1.0; }
                else      { t_bg  += (double)(-l1p); }
            } else if (mask) {
                const float d = x[e] - y[e];
                t_sq += (double)(d * d);
            }
        }
        const double bg    = (double)n_cells - face;
        const double scale = 1.0 + 1.0 / face;
        *out = (float)(scale * t_sq / (face * 4.0) + scale * t_bce / face + t_bg / bg);
    }
}

extern "C" void kernel_launch(void* const* d_in, const int* in_sizes, int n_in,
                              void* d_out, int out_size, void* d_ws, size_t ws_size,
                              hipStream_t stream) {
    const float* x = (const float*)d_in[0];
    const float* y = (const float*)d_in[1];
    float* out = (float*)d_out;
    float4* partials = (float4*)d_ws;

    const long long n_elems      = (long long)in_sizes[0];   // B*N*5
    const long long n_cells      = n_elems / 5;              // B*N
    const long long n_groups     = n_elems / 4;              // float4 groups
    const int       nsteps_total = (int)(n_groups / 64);     // 108160 for ref shape
    const long long covered      = (long long)nsteps_total * 256;

    // 1280 blocks = 5 resident blocks/CU x 256 CUs (32KB LDS each), one round.
    int nw = 5120;
    if (nsteps_total < nw) nw = (nsteps_total > 0) ? nsteps_total : 1;
    const int NB = (nw + WPB - 1) / WPB;

    if (nsteps_total > 0)
        mloss_reduce<<<NB, BLOCK, 0, stream>>>(x, y, partials, nsteps_total, nw);
    mloss_final<<<1, FBLOCK, 0, stream>>>(partials, (nsteps_total > 0) ? NB : 0,
                                          x, y, out, covered, n_elems, n_cells);
}

// Round 5
// 230.953 us; speedup vs baseline: 1.0879x; 1.0879x over previous
//
#include <hip/hip_runtime.h>

// MLoss: masked box-MSE + face-BCE + background-BCE over [B=2048, N=2704, C=5].
// 221.5 MB read once per launch. Reduce kernel history:
//   R2   atomic-free two-stage reduction          (atomics = 270 us wall)
//   R3-5 82-84 us invariant to occupancy (20-65%)/VGPR/LDS/MLP/cache probes
//   R6   shfl for neighbor conf + nontemporal x -> 66 us
//   R7/8 reg double-buffer @ launch_bounds(256,8) -> spilled to scratch, 72 us
//   R9   same pipeline @ (256,4): spill gone (WRITE 64B), VGPR 40, pipeline
//        live -- STILL 65 us. Register-side MLP falsified as the lever.
//   R10  per-wave global_load_lds DMA ring, depth 4 (8KB/wave in flight,
//        no regalloc involvement): 102 us (occupancy 32%, LDS 33KB/block).
//        DMA-depth falsified too; FETCH unchanged (108.5MB) without nt.
//
// CONCLUSION (R11): the kernel runs at 221.5MB / 65us = 3.41 TB/s of pure
// READS. The m13 float4-copy "6.29 TB/s" ceiling is read+write summed (its
// read component ~3.15 TB/s; write-only fillBuffer measures 6.9 TB/s in our
// own profile). Read-streaming on this chip caps at ~3.2-3.4 TB/s -- a
// per-CU outstanding-miss x latency cap (~5KB/CU in flight / ~600-900cy
// blended), which explains the complete invariance to occupancy, register
// MLP, and DMA depth. Byte reduction is closed: the mask is data-dependent
// at 20B cells, so masked loads still touch ~89% of 64B lines. This source
// (R9's) is the best verified config: graded 227.9us, reduce 65.2us. At the
// read-path roofline.

#define BLOCK 256
#define TPC 2                    // tiles (256 groups each) per chunk, unrolled
#define LOG_CLAMP -100.0f

typedef float nvec4 __attribute__((ext_vector_type(4)));

__device__ __forceinline__ float clogf(float v) {
    return fmaxf(logf(v), LOG_CLAMP);
}

// One chunk's worth of in-flight data. All indexing is compile-time (full
// unroll) so this lives in registers: 2*(4+4)+2+2 = ~20 VGPRs per buffer.
struct ChunkBuf {
    nvec4  x4[TPC];
    float4 y4[TPC];
    float  yc0[TPC];
    int    rr[TPC];
};

__device__ __forceinline__ void load_chunk(
    int c, int wv, int lane,
    const nvec4* __restrict__ gx4, const float4* __restrict__ gy4,
    const float* __restrict__ y, ChunkBuf& b)
{
    #pragma unroll
    for (int k = 0; k < TPC; ++k) {
        const int g  = (c * TPC + k) * 256 + wv * 64 + lane;
        const int e0 = g * 4;
        const int r  = e0 % 5;
        b.rr[k]  = r;
        b.x4[k]  = __builtin_nontemporal_load(&gx4[g]);  // x: read-once, no alloc
        b.y4[k]  = gy4[g];
        // Lane 0 has no in-wave neighbor for the previous group's conf.
        b.yc0[k] = (lane == 0 && r != 0) ? y[e0 - r] : 0.0f;
    }
}

__device__ __forceinline__ void compute_chunk(
    const ChunkBuf& b, int lane,
    float& s_sq, float& s_bce, float& s_bg, float& s_cnt)
{
    #pragma unroll
    for (int k = 0; k < TPC; ++k) {
        const int    r = b.rr[k];
        const nvec4  X = b.x4[k];
        const float4 Y = b.y4[k];

        // Conf element of the cell starting inside this group (if any):
        // jc = (5-r)%5 < 4 for r != 1.
        const int jc = (5 - r) % 5;
        const float tnext = (jc == 0) ? Y.x : (jc == 1) ? Y.y : (jc == 2) ? Y.z : Y.w;
        const float pconf = (jc == 0) ? X.x : (jc == 1) ? X.y : (jc == 2) ? X.z : X.w;
        const bool  has_conf = (r != 1);

        const float lp  = clogf(pconf);
        const float l1p = clogf(1.0f - pconf);
        const bool  mc  = tnext > 0.5f;
        s_bce += (has_conf && mc)  ? -(tnext * lp + (1.0f - tnext) * l1p) : 0.0f;
        s_bg  += (has_conf && !mc) ? -l1p : 0.0f;
        s_cnt += (has_conf && mc)  ? 1.0f : 0.0f;

        // Conf of the cell containing e0: component (4-r_recv)&3 of lane
        // l-1's Y. Sender (r_s) side: r_recv=(r_s+4)%5 -> comp:
        // r_s=0 -> Y.x, r_s=2 -> Y.w, r_s=3 -> Y.z, r_s=4 -> Y.y (r_s=1 unused).
        const float outv = (r == 0) ? Y.x : (r == 2) ? Y.w : (r == 3) ? Y.z : Y.y;
        float ycp = __shfl_up(outv, 1, 64);
        if (lane == 0) ycp = b.yc0[k];
        const float yc = (r == 0) ? Y.x : ycp;

        // Box MSE: element j has m=r+j; m==0/5 is a conf element (skip);
        // cell conf is yc for m<5, tnext for m>5.
        #define MLOSS_BOX(J, XJ, YJ) do {                                 \
            const int   m  = r + (J);                                     \
            const bool  ic = (m == 0) || (m == 5);                        \
            const float tj = (m >= 5) ? tnext : yc;                       \
            const float d  = (XJ) - (YJ);                                 \
            s_sq += (!ic && tj > 0.5f) ? d * d : 0.0f;                    \
        } while (0)
        MLOSS_BOX(0, X.x, Y.x);
        MLOSS_BOX(1, X.y, Y.y);
        MLOSS_BOX(2, X.z, Y.z);
        MLOSS_BOX(3, X.w, Y.w);
        #undef MLOSS_BOX
    }
}

// Stage 1: grid-stride over chunks, register-double-buffered: chunk c+stride's
// loads are issued (and pinned by sched_barrier) before chunk c's compute, so
// the wave always has a full batch of loads in flight during compute.
__global__ __launch_bounds__(BLOCK, 4) void mloss_reduce(
    const float* __restrict__ x, const float* __restrict__ y,
    float4* __restrict__ partials, int n_chunks)
{
    const int lane = threadIdx.x & 63;
    const int wv   = threadIdx.x >> 6;

    const nvec4*  gx4 = (const nvec4*)x;
    const float4* gy4 = (const float4*)y;

    float s_sq = 0.0f, s_bce = 0.0f, s_bg = 0.0f, s_cnt = 0.0f;

    int c = blockIdx.x;
    const int stride = gridDim.x;
    if (c < n_chunks) {
        ChunkBuf A, B;
        load_chunk(c, wv, lane, gx4, gy4, y, A);
        c += stride;
        while (true) {
            if (c >= n_chunks) {
                compute_chunk(A, lane, s_sq, s_bce, s_bg, s_cnt);
                break;
            }
            load_chunk(c, wv, lane, gx4, gy4, y, B);
            __builtin_amdgcn_sched_barrier(0);   // pin B's loads before A's compute
            compute_chunk(A, lane, s_sq, s_bce, s_bg, s_cnt);
            c += stride;

            if (c >= n_chunks) {
                compute_chunk(B, lane, s_sq, s_bce, s_bg, s_cnt);
                break;
            }
            load_chunk(c, wv, lane, gx4, gy4, y, A);
            __builtin_amdgcn_sched_barrier(0);   // pin A's loads before B's compute
            compute_chunk(B, lane, s_sq, s_bce, s_bg, s_cnt);
            c += stride;
        }
    }

    // ---- Wave-64 butterfly reduce, then cross-wave via LDS ----
    #pragma unroll
    for (int off = 32; off > 0; off >>= 1) {
        s_sq  += __shfl_down(s_sq,  off, 64);
        s_bce += __shfl_down(s_bce, off, 64);
        s_bg  += __shfl_down(s_bg,  off, 64);
        s_cnt += __shfl_down(s_cnt, off, 64);
    }
    __shared__ float4 r_part[BLOCK / 64];
    if (lane == 0) r_part[wv] = make_float4(s_sq, s_bce, s_bg, s_cnt);
    __syncthreads();
    if (threadIdx.x == 0) {
        float4 t0 = r_part[0];
        #pragma unroll
        for (int w = 1; w < BLOCK / 64; ++w) {
            t0.x += r_part[w].x; t0.y += r_part[w].y;
            t0.z += r_part[w].z; t0.w += r_part[w].w;
        }
        partials[blockIdx.x] = t0;
    }
}

// Stage 2: one block reduces per-block partials (double accumulation),
// mops up tail elements not covered by full chunks, computes the scalar.
#define FBLOCK 1024
__global__ __launch_bounds__(FBLOCK) void mloss_final(
    const float4* __restrict__ partials, int n_parts,
    const float* __restrict__ x, const float* __restrict__ y,
    float* __restrict__ out, long long elem_start, long long n_elems,
    long long n_cells)
{
    double s_sq = 0.0, s_bce = 0.0, s_bg = 0.0, s_cnt = 0.0;
    for (int i = threadIdx.x; i < n_parts; i += FBLOCK) {
        const float4 v = partials[i];
        s_sq += (double)v.x; s_bce += (double)v.y;
        s_bg += (double)v.z; s_cnt += (double)v.w;
    }

    #pragma unroll
    for (int off = 32; off > 0; off >>= 1) {
        s_sq  += __shfl_down(s_sq,  off, 64);
        s_bce += __shfl_down(s_bce, off, 64);
        s_bg  += __shfl_down(s_bg,  off, 64);
        s_cnt += __shfl_down(s_cnt, off, 64);
    }

    __shared__ double r[FBLOCK / 64][4];
    const int wave = threadIdx.x >> 6;
    const int lane = threadIdx.x & 63;
    if (lane == 0) { r[wave][0] = s_sq; r[wave][1] = s_bce; r[wave][2] = s_bg; r[wave][3] = s_cnt; }
    __syncthreads();

    if (threadIdx.x == 0) {
        double t_sq = 0.0, t_bce = 0.0, t_bg = 0.0, face = 0.0;
        #pragma unroll
        for (int w = 0; w < FBLOCK / 64; ++w) {
            t_sq += r[w][0]; t_bce += r[w][1]; t_bg += r[w][2]; face += r[w][3];
        }
        for (long long e = elem_start; e < n_elems; ++e) {
            const long long m  = e % 5;
            const float t_cell = y[e - m];
            const bool  mask   = t_cell > 0.5f;
            if (m == 0) {
                const float p   = x[e];
                const float lp  = clogf(p);
                const float l1p = clogf(1.0f - p);
                if (mask) { t_bce += (double)(-(t_cell * lp + (1.0f - t_cell) * l1p)); face += 1.0; }
                else      { t_bg  += (double)(-l1p); }
            } else if (mask) {
                const float d = x[e] - y[e];
                t_sq += (double)(d * d);
            }
        }
        const double bg    = (double)n_cells - face;
        const double scale = 1.0 + 1.0 / face;
        *out = (float)(scale * t_sq / (face * 4.0) + scale * t_bce / face + t_bg / bg);
    }
}

extern "C" void kernel_launch(void* const* d_in, const int* in_sizes, int n_in,
                              void* d_out, int out_size, void* d_ws, size_t ws_size,
                              hipStream_t stream) {
    const float* x = (const float*)d_in[0];
    const float* y = (const float*)d_in[1];
    float* out = (float*)d_out;
    float4* partials = (float4*)d_ws;

    const long long n_elems  = (long long)in_sizes[0];   // B*N*5
    const long long n_cells  = n_elems / 5;              // B*N
    const long long n_groups = n_elems / 4;              // float4 groups
    const long long n_tiles  = n_groups / 256;           // 27040 for ref shape
    const int       n_chunks = (int)(n_tiles / TPC);     // 13520 for ref shape
    const long long covered  = (long long)n_chunks * TPC * 256 * 4;

    const int NB = (n_chunks < 2048) ? (n_chunks > 0 ? n_chunks : 1) : 2048;

    if (n_chunks > 0)
        mloss_reduce<<<NB, BLOCK, 0, stream>>>(x, y, partials, n_chunks);
    mloss_final<<<1, FBLOCK, 0, stream>>>(partials, (n_chunks > 0) ? NB : 0,
                                          x, y, out, covered, n_elems, n_cells);
}